// Round 1
// 694.547 us; speedup vs baseline: 1.7632x; 1.7632x over previous
//
#include <hip/hip_runtime.h>

// Fused Swin-style window attention for MI355X (gfx950), v2.
// One block (256 thr / 4 waves) per 8x8 window. FP16 MFMA (16x16x32), fp32 acc.
// Key changes vs v1:
//  - QKV projection tiled 64tok x 64col per wave (3 passes): each w_in row read
//    by exactly ONE wave -> L2 weight traffic 1.5MB -> 384KB per block.
//  - wave wv owns heads 2wv,2wv+1 end-to-end: attention is wave-local, only 5
//    block barriers total (was ~18).
//  - scores computed transposed (mfma(K,Q)): softmax reduce = 2 shuffles;
//    1/sum deferred to PV output; 1/sqrt(32) folded into exp2 argument.
//  - XN LDS buffer XOR-chunk-swizzled (chunk ^= row>>3): kills the 16-way
//    phase-0 write conflict (was the 3.9e7 SQ_LDS_BANK_CONFLICT).
//  - XCD-bijective blockIdx remap: all 16 windows of an h-row share one XCD L2.

typedef _Float16 half8  __attribute__((ext_vector_type(8)));
typedef _Float16 half2v __attribute__((ext_vector_type(2)));
typedef float    f32x4  __attribute__((ext_vector_type(4)));

#define XN_STR 264
#define XN_SZ  (64 * XN_STR)          // 16896 halfs (33792 B), reused as P slots & obuf
#define S_STR  72
#define S_SZ   (64 * S_STR)           // 4608 halfs per-wave scratch (Q/K/VT)
#define SM_TOT (XN_SZ + 4 * S_SZ)     // 35328 halfs = 70656 B (+2KB s_gb = 72.7KB)

// XN addr: [row 0..63][c 0..255], 16B-chunk XOR swizzle keyed by row>>3.
__device__ __forceinline__ int xn_idx(int row, int c) {
    return row * XN_STR + (((c >> 3) ^ (row >> 3)) << 3) + (c & 7);
}
// P slot addr: [q 0..63][k 0..63], chunk swizzle keyed by q&7 (row stride 128B).
__device__ __forceinline__ int p_idx(int q, int k) {
    return q * 64 + (((k >> 3) ^ (q & 7)) << 3) + (k & 7);
}

__global__ void __launch_bounds__(256)
prep_weights_f16(const float* __restrict__ w_in, const float* __restrict__ w_out,
                 _Float16* __restrict__ wh) {
    int i = blockIdx.x * 256 + threadIdx.x;
    if (i < 196608)      wh[i] = (_Float16)w_in[i];
    else if (i < 262144) wh[i] = (_Float16)w_out[i - 196608];
}

__global__ void __launch_bounds__(256, 2)
win_attn_fused(const float* __restrict__ x, const float* __restrict__ gamma,
               const float* __restrict__ beta, const float* __restrict__ b_in,
               const float* __restrict__ b_out,
               const _Float16* __restrict__ w_in_h,
               const _Float16* __restrict__ w_out_h,
               float* __restrict__ out)
{
    __shared__ __align__(16) _Float16 sm[SM_TOT];
    __shared__ float s_gb[512];

    const int tid  = threadIdx.x;
    // XCD-bijective remap (4096 blocks, 8 XCDs): each XCD gets 512 consecutive
    // logical windows -> all 16 wwi of an h-row share one XCD's L2.
    const int bidr = blockIdx.x;
    const int wid  = (bidr & 7) * 512 + (bidr >> 3);
    const int b    = wid >> 8;
    const int whi  = (wid >> 4) & 15;
    const int wwi  = wid & 15;
    const int h0 = whi * 8, w0 = wwi * 8;

    s_gb[tid]       = gamma[tid];
    s_gb[256 + tid] = beta[tid];

    const int wv   = tid >> 6;
    const int lane = tid & 63;
    const int quad = lane >> 4;
    const int l16  = lane & 15;

    // ---- phase 0: gather window -> XN [tok][c] fp16 (swizzled) ----
    {
        const int th = lane & 7;            // row-octet index == swizzle key
        const int qq = (lane >> 3) & 1;
        const int cg = wv * 4 + (lane >> 4);
        const int t0 = th * 8 + qq * 4;
        const float* xb = x + (((size_t)b * 256) * 128 + h0) * 128 + w0;
#pragma unroll
        for (int it = 0; it < 16; ++it) {
            int c = it * 16 + cg;
            float4 v = *(const float4*)(xb + ((size_t)c * 128 + th) * 128 + qq * 4);
            // (t0+r)>>3 == th for r=0..3, so one swizzled base serves all 4 rows
            int base = t0 * XN_STR + (((c >> 3) ^ th) << 3) + (c & 7);
            sm[base]              = (_Float16)v.x;
            sm[base + XN_STR]     = (_Float16)v.y;
            sm[base + 2 * XN_STR] = (_Float16)v.z;
            sm[base + 3 * XN_STR] = (_Float16)v.w;
        }
    }
    __syncthreads();

    // ---- LayerNorm in place (4 threads per token, butterfly stats) ----
    {
        const int tok = tid >> 2, cq = tid & 3;
        float sum = 0.f, ss = 0.f;
        half8 hv[8];
#pragma unroll
        for (int k2 = 0; k2 < 8; ++k2) {
            hv[k2] = *(const half8*)&sm[xn_idx(tok, cq * 64 + k2 * 8)];
#pragma unroll
            for (int j = 0; j < 8; ++j) { float f = (float)hv[k2][j]; sum += f; ss += f * f; }
        }
        sum += __shfl_xor(sum, 1); ss += __shfl_xor(ss, 1);
        sum += __shfl_xor(sum, 2); ss += __shfl_xor(ss, 2);
        float mu   = sum * (1.f / 256.f);
        float var  = ss * (1.f / 256.f) - mu * mu;
        float rstd = rsqrtf(var + 1e-5f);
#pragma unroll
        for (int k2 = 0; k2 < 8; ++k2) {
            int c0 = cq * 64 + k2 * 8;
            float4 g0 = *(const float4*)&s_gb[c0];
            float4 g1 = *(const float4*)&s_gb[c0 + 4];
            float4 e0 = *(const float4*)&s_gb[256 + c0];
            float4 e1 = *(const float4*)&s_gb[256 + c0 + 4];
            float gg[8] = {g0.x, g0.y, g0.z, g0.w, g1.x, g1.y, g1.z, g1.w};
            float bb[8] = {e0.x, e0.y, e0.z, e0.w, e1.x, e1.y, e1.z, e1.w};
            half8 o;
#pragma unroll
            for (int j = 0; j < 8; ++j)
                o[j] = (_Float16)(((float)hv[k2][j] - mu) * rstd * gg[j] + bb[j]);
            *(half8*)&sm[xn_idx(tok, c0)] = o;
        }
    }
    __syncthreads();

    const f32x4 zero4 = {0.f, 0.f, 0.f, 0.f};
    _Float16* Swv = &sm[XN_SZ + wv * S_SZ];   // per-wave scratch [64][72]

    // 64tok x 64col GEMM vs w_in cols [p*256 + wv*64, +64) -- each weight row
    // read by exactly one wave.
    auto qkv_pass = [&](const int p, f32x4 (&acc)[4][4]) {
#pragma unroll
        for (int mt = 0; mt < 4; ++mt)
#pragma unroll
            for (int nt = 0; nt < 4; ++nt) acc[mt][nt] = zero4;
        const _Float16* wb = w_in_h + (size_t)(p * 256 + wv * 64) * 256 + quad * 8;
#pragma unroll
        for (int kb = 0; kb < 256; kb += 32) {
            half8 af[4], bf[4];
#pragma unroll
            for (int mt = 0; mt < 4; ++mt)
                af[mt] = *(const half8*)&sm[xn_idx(mt * 16 + l16, kb + quad * 8)];
#pragma unroll
            for (int nt = 0; nt < 4; ++nt)
                bf[nt] = *(const half8*)(wb + (size_t)(nt * 16 + l16) * 256 + kb);
#pragma unroll
            for (int mt = 0; mt < 4; ++mt)
#pragma unroll
                for (int nt = 0; nt < 4; ++nt)
                    acc[mt][nt] = __builtin_amdgcn_mfma_f32_16x16x32_f16(af[mt], bf[nt], acc[mt][nt], 0, 0, 0);
        }
#pragma unroll
        for (int nt = 0; nt < 4; ++nt) {
            float bi = b_in[p * 256 + wv * 64 + nt * 16 + l16];
#pragma unroll
            for (int mt = 0; mt < 4; ++mt) {
                acc[mt][nt][0] += bi; acc[mt][nt][1] += bi;
                acc[mt][nt][2] += bi; acc[mt][nt][3] += bi;
            }
        }
    };

    half8 qfrag[2][4], kfrag[2][4];   // [head-half][16-row tile]

    // ---- pass Q: GEMM -> scratch [tok][64] -> hoist row-fragments ----
    {
        f32x4 acc[4][4];
        qkv_pass(0, acc);
#pragma unroll
        for (int mt = 0; mt < 4; ++mt)
#pragma unroll
            for (int nt = 0; nt < 4; ++nt)
#pragma unroll
                for (int r = 0; r < 4; ++r)
                    Swv[(mt * 16 + quad * 4 + r) * S_STR + nt * 16 + l16] = (_Float16)acc[mt][nt][r];
        asm volatile("s_waitcnt lgkmcnt(0)" ::: "memory");
        __builtin_amdgcn_sched_barrier(0);
#pragma unroll
        for (int hh = 0; hh < 2; ++hh)
#pragma unroll
            for (int nt = 0; nt < 4; ++nt)
                qfrag[hh][nt] = *(const half8*)&Swv[(nt * 16 + l16) * S_STR + hh * 32 + quad * 8];
    }
    asm volatile("s_waitcnt lgkmcnt(0)" ::: "memory");
    __builtin_amdgcn_sched_barrier(0);

    // ---- pass K ----
    {
        f32x4 acc[4][4];
        qkv_pass(1, acc);
#pragma unroll
        for (int mt = 0; mt < 4; ++mt)
#pragma unroll
            for (int nt = 0; nt < 4; ++nt)
#pragma unroll
                for (int r = 0; r < 4; ++r)
                    Swv[(mt * 16 + quad * 4 + r) * S_STR + nt * 16 + l16] = (_Float16)acc[mt][nt][r];
        asm volatile("s_waitcnt lgkmcnt(0)" ::: "memory");
        __builtin_amdgcn_sched_barrier(0);
#pragma unroll
        for (int hh = 0; hh < 2; ++hh)
#pragma unroll
            for (int nt = 0; nt < 4; ++nt)
                kfrag[hh][nt] = *(const half8*)&Swv[(nt * 16 + l16) * S_STR + hh * 32 + quad * 8];
    }
    asm volatile("s_waitcnt lgkmcnt(0)" ::: "memory");
    __builtin_amdgcn_sched_barrier(0);

    // ---- pass V: GEMM -> scratch transposed VT [dh 64][tok 64] ----
    {
        f32x4 acc[4][4];
        qkv_pass(2, acc);
#pragma unroll
        for (int mt = 0; mt < 4; ++mt)
#pragma unroll
            for (int nt = 0; nt < 4; ++nt)
#pragma unroll
                for (int rp = 0; rp < 2; ++rp) {
                    half2v pk = { (_Float16)acc[mt][nt][2 * rp], (_Float16)acc[mt][nt][2 * rp + 1] };
                    *(half2v*)&Swv[(nt * 16 + l16) * S_STR + mt * 16 + quad * 4 + 2 * rp] = pk;
                }
    }
    __syncthreads();   // all waves done reading XN -> XN region reusable as P slots

    // ---- attention: wave wv handles heads 2wv, 2wv+1 entirely ----
    f32x4 oacc[2][2][4];     // [head][dh-tile][q-tile], out^T, unnormalized
    float rs[2][4];          // 1/sum per (head, q-tile) for this lane's column
    _Float16* Pw = &sm[wv * 4096];   // per-wave P slot inside XN region

#pragma unroll
    for (int hh = 0; hh < 2; ++hh) {
        // scores^T: D[ktok][qtok] = K . Q  (K=32 -> one MFMA per 16x16 tile)
        f32x4 s[4][4];
#pragma unroll
        for (int mt = 0; mt < 4; ++mt)
#pragma unroll
            for (int nt = 0; nt < 4; ++nt)
                s[mt][nt] = __builtin_amdgcn_mfma_f32_16x16x32_f16(kfrag[hh][mt], qfrag[hh][nt], zero4, 0, 0, 0);

        // softmax over ktok (per column q): 16 in-lane + 2 shuffles.
        // scale 1/sqrt(32) folded into exp2 arg (max commutes with pos. scale).
        const float SC = 0.17677669529663687f * 1.4426950408889634f;
#pragma unroll
        for (int nt = 0; nt < 4; ++nt) {
            float m = -3.0e38f;
#pragma unroll
            for (int mt = 0; mt < 4; ++mt)
#pragma unroll
                for (int r = 0; r < 4; ++r) m = fmaxf(m, s[mt][nt][r]);
            m = fmaxf(m, __shfl_xor(m, 16));
            m = fmaxf(m, __shfl_xor(m, 32));
            float sum = 0.f;
#pragma unroll
            for (int mt = 0; mt < 4; ++mt)
#pragma unroll
                for (int r = 0; r < 4; ++r) {
                    float e = exp2f((s[mt][nt][r] - m) * SC);
                    s[mt][nt][r] = e; sum += e;
                }
            sum += __shfl_xor(sum, 16);
            sum += __shfl_xor(sum, 32);
            rs[hh][nt] = 1.f / sum;
        }

        // write P~ (q-row-major, k-contiguous) -> swizzled P slot, b32 packed
#pragma unroll
        for (int nt = 0; nt < 4; ++nt) {
            int q = nt * 16 + l16;
#pragma unroll
            for (int mt = 0; mt < 4; ++mt) {
                int k0 = mt * 16 + quad * 4;
                int a0 = p_idx(q, k0);
                half2v lo = { (_Float16)s[mt][nt][0], (_Float16)s[mt][nt][1] };
                half2v hi = { (_Float16)s[mt][nt][2], (_Float16)s[mt][nt][3] };
                *(half2v*)&Pw[a0]     = lo;
                *(half2v*)&Pw[a0 + 2] = hi;
            }
        }
        asm volatile("s_waitcnt lgkmcnt(0)" ::: "memory");
        __builtin_amdgcn_sched_barrier(0);

        // PV: out^T[dh][q] = VT . P~   (M=32, N=64, K=64)
#pragma unroll
        for (int mtv = 0; mtv < 2; ++mtv)
#pragma unroll
            for (int nt = 0; nt < 4; ++nt) oacc[hh][mtv][nt] = zero4;
#pragma unroll
        for (int kb = 0; kb < 2; ++kb) {
            half8 av[2], bp[4];
#pragma unroll
            for (int mtv = 0; mtv < 2; ++mtv)
                av[mtv] = *(const half8*)&Swv[(hh * 32 + mtv * 16 + l16) * S_STR + kb * 32 + quad * 8];
#pragma unroll
            for (int nt = 0; nt < 4; ++nt)
                bp[nt] = *(const half8*)&Pw[p_idx(nt * 16 + l16, kb * 32 + quad * 8)];
#pragma unroll
            for (int mtv = 0; mtv < 2; ++mtv)
#pragma unroll
                for (int nt = 0; nt < 4; ++nt)
                    oacc[hh][mtv][nt] = __builtin_amdgcn_mfma_f32_16x16x32_f16(av[mtv], bp[nt], oacc[hh][mtv][nt], 0, 0, 0);
        }
    }
    __syncthreads();   // all waves done with P slots -> XN region reusable as obuf

    // ---- phase 2: normalized attn output -> obuf[tok][c] (XN region, swizzled)
    // wave wv owns cols 64wv..64wv+63; softmax 1/sum applied here.
#pragma unroll
    for (int hh = 0; hh < 2; ++hh)
#pragma unroll
        for (int mtv = 0; mtv < 2; ++mtv)
#pragma unroll
            for (int nt = 0; nt < 4; ++nt) {
                int tok = nt * 16 + l16;
                int c0  = (2 * wv + hh) * 32 + mtv * 16 + quad * 4;
                float sc = rs[hh][nt];
                int a0 = xn_idx(tok, c0);
                half2v lo = { (_Float16)(oacc[hh][mtv][nt][0] * sc), (_Float16)(oacc[hh][mtv][nt][1] * sc) };
                half2v hi = { (_Float16)(oacc[hh][mtv][nt][2] * sc), (_Float16)(oacc[hh][mtv][nt][3] * sc) };
                *(half2v*)&sm[a0]     = lo;
                *(half2v*)&sm[a0 + 2] = hi;
            }
    __syncthreads();

    // ---- phase 3: y^T = w_out . obuf^T  (each wave owns 64 distinct w_out rows)
    f32x4 pacc[4][4];
#pragma unroll
    for (int mt = 0; mt < 4; ++mt)
#pragma unroll
        for (int nt = 0; nt < 4; ++nt) pacc[mt][nt] = zero4;
    const _Float16* wor = w_out_h + (size_t)(64 * wv + l16) * 256 + quad * 8;
#pragma unroll
    for (int kb = 0; kb < 256; kb += 32) {
        half8 aw[4], bo[4];
#pragma unroll
        for (int mt = 0; mt < 4; ++mt) aw[mt] = *(const half8*)(wor + mt * 16 * 256 + kb);
#pragma unroll
        for (int nt = 0; nt < 4; ++nt)
            bo[nt] = *(const half8*)&sm[xn_idx(nt * 16 + l16, kb + quad * 8)];
#pragma unroll
        for (int mt = 0; mt < 4; ++mt)
#pragma unroll
            for (int nt = 0; nt < 4; ++nt)
                pacc[mt][nt] = __builtin_amdgcn_mfma_f32_16x16x32_f16(aw[mt], bo[nt], pacc[mt][nt], 0, 0, 0);
    }

    // ---- epilogue: bias + scatter to (B,C,H,W) fp32 ----
    float* ob = out + (((size_t)b * 256) * 128 + h0) * 128 + w0;
#pragma unroll
    for (int mt = 0; mt < 4; ++mt) {
#pragma unroll
        for (int r = 0; r < 4; ++r) {
            int c = 64 * wv + mt * 16 + quad * 4 + r;
            float bi = b_out[c];
#pragma unroll
            for (int nt = 0; nt < 4; ++nt) {
                int tok = nt * 16 + l16;
                ob[((size_t)c * 128 + (tok >> 3)) * 128 + (tok & 7)] = pacc[mt][nt][r] + bi;
            }
        }
    }
}

extern "C" void kernel_launch(void* const* d_in, const int* in_sizes, int n_in,
                              void* d_out, int out_size, void* d_ws, size_t ws_size,
                              hipStream_t stream) {
    const float* x        = (const float*)d_in[0];
    const float* ln_gamma = (const float*)d_in[1];
    const float* ln_beta  = (const float*)d_in[2];
    const float* w_in     = (const float*)d_in[3];
    const float* b_in     = (const float*)d_in[4];
    const float* w_out    = (const float*)d_in[5];
    const float* b_out    = (const float*)d_in[6];
    float* y = (float*)d_out;

    _Float16* w_in_h  = (_Float16*)d_ws;            // 196608 halfs
    _Float16* w_out_h = w_in_h + 196608;            // 65536 halfs

    prep_weights_f16<<<1024, 256, 0, stream>>>(w_in, w_out, w_in_h);
    win_attn_fused<<<4096, 256, 0, stream>>>(x, ln_gamma, ln_beta, b_in, b_out,
                                             w_in_h, w_out_h, y);
}